// Round 1
// 693.268 us; speedup vs baseline: 1.0260x; 1.0260x over previous
//
#include <hip/hip_runtime.h>

// Problem constants (from reference setup_inputs)
#define Bb 2
#define Nn 1024
#define Ee 8192
#define DV 64   // IN_V == OUT_V == IN_E == 64

typedef __attribute__((ext_vector_type(8))) short short8;
typedef __attribute__((ext_vector_type(8))) unsigned short ushort8;
typedef __attribute__((ext_vector_type(4))) float floatx4;

// fp32 -> bf16 bits, round-to-nearest-even
static __device__ __forceinline__ unsigned short f2bf(float f) {
    unsigned int u = __float_as_uint(f);
    unsigned int r = (u + 0x7FFFu + ((u >> 16) & 1u)) >> 16;
    return (unsigned short)r;
}
static __device__ __forceinline__ float bf2f(unsigned short u) {
    return __uint_as_float(((unsigned int)u) << 16);
}

// scale[b*E + e] = dot(H_e[row,:64], p[:64]); one wave per row
__global__ __launch_bounds__(256) void scale_kernel(const float* __restrict__ He,
                                                    const float* __restrict__ p,
                                                    float* __restrict__ scale) {
    int wave = threadIdx.x >> 6;
    int lane = threadIdx.x & 63;
    int row = blockIdx.x * 4 + wave;
    float v = He[row * 64 + lane] * p[lane];
    #pragma unroll
    for (int off = 32; off > 0; off >>= 1) v += __shfl_xor(v, off);
    if (lane == 0) scale[row] = v;
}

// Pre-cast T (fp32) -> Tsc (bf16, scaled by scale[e]) and Tpl (bf16, plain)
__global__ __launch_bounds__(256) void cast_kernel(const float* __restrict__ T,
                                                   const float* __restrict__ scale,
                                                   unsigned short* __restrict__ Tsc,
                                                   unsigned short* __restrict__ Tpl) {
    size_t i4 = (size_t)blockIdx.x * 256 + threadIdx.x;   // float4 index
    size_t e0 = i4 * 4;                                   // element index
    int b = (int)(e0 >> 23);                              // 2^23 elems per batch
    int e = (int)(e0 & 8191);                             // column within row
    floatx4 t = *(const floatx4*)&T[e0];
    floatx4 s = *(const floatx4*)&scale[(size_t)b * Ee + e];
    ushort4 sc, pl;
    sc.x = f2bf(t.x * s.x); sc.y = f2bf(t.y * s.y);
    sc.z = f2bf(t.z * s.z); sc.w = f2bf(t.w * s.w);
    pl.x = f2bf(t.x); pl.y = f2bf(t.y);
    pl.z = f2bf(t.z); pl.w = f2bf(t.w);
    *(ushort4*)&Tsc[e0] = sc;
    *(ushort4*)&Tpl[e0] = pl;
}

// HW = H_v @ weight   [B*N,64] @ [64,64]
__global__ __launch_bounds__(256) void hw_kernel(const float* __restrict__ Hv,
                                                 const float* __restrict__ W,
                                                 float* __restrict__ HWo) {
    __shared__ float Ws[64 * 64];
    __shared__ float Hvs[4 * 64];
    int t = threadIdx.x;
    for (int i = t; i < 4096; i += 256) Ws[i] = W[i];
    int r0 = blockIdx.x * 4;
    Hvs[t] = Hv[(size_t)r0 * 64 + t];
    __syncthreads();
    int d = t & 63, rr = t >> 6;
    float acc = 0.f;
    #pragma unroll
    for (int c = 0; c < 64; ++c) acc += Hvs[rr * 64 + c] * Ws[c * 64 + d];
    HWo[(size_t)(r0 + rr) * 64 + d] = acc;
}

// Partial M1 tiles: upper-triangular 128x128 tiles, K-split 7, bf16 partial store.
// R1: double-buffered LDS pipeline (T3-minimum): STAGE(next) issued BEFORE
// compute(cur); single vmcnt(0)+barrier per K-tile (the __syncthreads drain)
// so global-load latency hides under the MFMA/ds_read phase.
__global__ __launch_bounds__(256, 2) void mm_kernel(const unsigned short* __restrict__ Tsc,
                                                    const unsigned short* __restrict__ Tpl,
                                                    unsigned short* __restrict__ Ppart) {
    __shared__ __attribute__((aligned(16))) unsigned short As[2][128 * 64];
    __shared__ __attribute__((aligned(16))) unsigned short Bs[2][128 * 64];
    const int t = threadIdx.x;
    const int tile = blockIdx.x;     // 0..35 upper-triangular
    const int b = blockIdx.y;
    const int s = blockIdx.z;        // 0..6 K-split

    int i = 0, rem = tile;
    while (rem >= 8 - i) { rem -= 8 - i; ++i; }
    const int j = i + rem;
    const int n0 = i * 128, m0 = j * 128;

    const int lane = t & 63;
    const int w = t >> 6;
    const int wr = w >> 1, wc = w & 1;      // 2x2 wave grid, each wave 64x64
    const int quad = lane >> 4;
    const int l15 = lane & 15;
    const int l7 = l15 & 7;

    const int lr = lane >> 3;               // row within staged 8-row group
    const int lc = (lane & 7) ^ lr;         // swizzled global chunk this lane fetches

    const int kc0 = (s * 128) / 7 * 64;
    const int kc1 = ((s + 1) * 128) / 7 * 64;
    const int nIter = (kc1 - kc0) >> 6;     // 18 or 19

    const unsigned short* gA = Tsc + ((size_t)b * Nn + n0 + w * 32 + lr) * Ee + kc0 + lc * 8;
    const unsigned short* gB = Tpl + ((size_t)b * Nn + m0 + w * 32 + lr) * Ee + kc0 + lc * 8;
    const int ldsOff = (w * 32) * 64 + lane * 8;   // ushort offset within a buffer

    floatx4 acc[4][4];
    #pragma unroll
    for (int a = 0; a < 4; ++a)
        #pragma unroll
        for (int c = 0; c < 4; ++c) acc[a][c] = (floatx4){0.f, 0.f, 0.f, 0.f};

    auto STAGE = [&](int buf) {
        unsigned short* lA = &As[buf][0] + ldsOff;
        unsigned short* lB = &Bs[buf][0] + ldsOff;
        #pragma unroll
        for (int u = 0; u < 4; ++u) {
            __builtin_amdgcn_global_load_lds(
                (const __attribute__((address_space(1))) unsigned int*)(gA + (size_t)u * 8 * Ee),
                (__attribute__((address_space(3))) unsigned int*)(lA + u * 8 * 64), 16, 0, 0);
            __builtin_amdgcn_global_load_lds(
                (const __attribute__((address_space(1))) unsigned int*)(gB + (size_t)u * 8 * Ee),
                (__attribute__((address_space(3))) unsigned int*)(lB + u * 8 * 64), 16, 0, 0);
        }
        gA += 64; gB += 64;
    };

    STAGE(0);
    __syncthreads();                         // drains vmcnt(0): buf0 ready
    for (int it = 0; it < nIter; ++it) {
        if (it + 1 < nIter) STAGE((it + 1) & 1);   // prefetch next K-tile (in flight during compute)
        const unsigned short* Ac = &As[it & 1][0];
        const unsigned short* Bc = &Bs[it & 1][0];
        #pragma unroll
        for (int kk8 = 0; kk8 < 8; kk8 += 4) {
            short8 af[4], bf[4];
            #pragma unroll
            for (int a = 0; a < 4; ++a)
                af[a] = *(const short8*)&Ac[(wr * 64 + a * 16 + l15) * 64 + ((kk8 + quad) ^ l7) * 8];
            #pragma unroll
            for (int c = 0; c < 4; ++c)
                bf[c] = *(const short8*)&Bc[(wc * 64 + c * 16 + l15) * 64 + ((kk8 + quad) ^ l7) * 8];
            #pragma unroll
            for (int a = 0; a < 4; ++a)
                #pragma unroll
                for (int c = 0; c < 4; ++c)
                    acc[a][c] = __builtin_amdgcn_mfma_f32_16x16x32_bf16(af[a], bf[c], acc[a][c], 0, 0, 0);
        }
        __syncthreads();   // drains vmcnt(0) (prefetch landed) + lgkm; safe to reuse buffers
    }

    unsigned short* P = Ppart + (((size_t)(b * 36 + tile)) * 7 + s) * 16384;
    #pragma unroll
    for (int a = 0; a < 4; ++a)
        #pragma unroll
        for (int c = 0; c < 4; ++c)
            #pragma unroll
            for (int v = 0; v < 4; ++v) {
                int r = wr * 64 + a * 16 + quad * 4 + v;
                int cc = wc * 64 + c * 16 + l15;
                P[r * 128 + cc] = f2bf(acc[a][c][v]);
            }
}

// Fused: sum K-split partials (bf16) for one 64x64 quadrant of an upper-tri tile,
// diag override, Hadamard both orientations (fp32), two 64x64x64 GEMMs vs HW.
// R1: NO atomics. Each contribution is uniquely (row-block r, col-block k):
//   GEMM1 of (i,j,qr,qc): r=2i+qr, k=2j+qc  (k>=r region, incl. diagonal tiles)
//   GEMM2 of (i<j,qr,qc): r=2j+qc, k=2i+qr  (k<r region)
// Coverage over k=0..15 is exact & disjoint -> plain float4 stores into
// parts[k][b,n,d]; reduce_kernel sums the 16 slices + bias.
__global__ __launch_bounds__(256) void fuse_kernel(const unsigned short* __restrict__ Ppart,
                                                   const float* __restrict__ adj_v,
                                                   const float* __restrict__ HWo,
                                                   float* __restrict__ parts) {
    __shared__ float Ls[64 * 68];    // raw M1 sums (pad 68: 16B-aligned rows)
    __shared__ float Lsn[64 * 68];   // sums * adj_v[n,m]
    __shared__ float Lst[64 * 68];   // transposed sums * adj_v[m,n]
    const int t = threadIdx.x;
    const int job = blockIdx.x;      // 0..71
    const int quad = blockIdx.y;     // 0..3
    const int b = job / 36;
    const int tile = job % 36;
    int i = 0, rem = tile;
    while (rem >= 8 - i) { rem -= 8 - i; ++i; }
    const int j = i + rem;
    const int qr = quad >> 1, qc = quad & 1;
    const int n0 = i * 128 + qr * 64;   // global row base of quadrant
    const int m0 = j * 128 + qc * 64;   // global col base of quadrant
    const unsigned short* P = Ppart + (size_t)job * 7 * 16384 + (qr * 64) * 128 + qc * 64;
    const float* AV = adj_v + (size_t)b * Nn * Nn;
    const float* HW = HWo + (size_t)b * Nn * 64;

    // Phase A: sum 7 bf16 partials -> Ls; Lsn = Ls * AV[n,m] (+ diag override)
    {
        int r = t >> 2, c0 = (t & 3) * 16;
        float sv[16];
        #pragma unroll
        for (int x = 0; x < 16; ++x) sv[x] = 0.f;
        #pragma unroll
        for (int sp = 0; sp < 7; ++sp) {
            const unsigned short* ps = P + sp * 16384 + r * 128 + c0;
            ushort8 u0 = *(const ushort8*)ps;
            ushort8 u1 = *(const ushort8*)(ps + 8);
            #pragma unroll
            for (int x = 0; x < 8; ++x) {
                sv[x] += bf2f(u0[x]);
                sv[8 + x] += bf2f(u1[x]);
            }
        }
        if (i == j && qr == qc) {
            int dcol = r - c0;   // gn==gm  <=>  local r == local c
            if (dcol >= 0 && dcol < 16) sv[dcol] = 1.0f;
        }
        #pragma unroll
        for (int x4 = 0; x4 < 4; ++x4) {
            floatx4 v = (floatx4){sv[x4 * 4], sv[x4 * 4 + 1], sv[x4 * 4 + 2], sv[x4 * 4 + 3]};
            *(floatx4*)&Ls[r * 68 + c0 + x4 * 4] = v;
            floatx4 a = *(const floatx4*)&AV[(size_t)(n0 + r) * Nn + m0 + c0 + x4 * 4];
            floatx4 o = (floatx4){v.x * a.x, v.y * a.y, v.z * a.z, v.w * a.w};
            *(floatx4*)&Lsn[r * 68 + c0 + x4 * 4] = o;
        }
    }
    __syncthreads();
    // Phase B: Lst[m][r] = Ls[r][m] * AV[m0+m][n0+r]  (off-diag tiles only)
    if (i != j) {
        int m = t >> 2, r0 = (t & 3) * 16;
        #pragma unroll
        for (int x4 = 0; x4 < 4; ++x4) {
            floatx4 a = *(const floatx4*)&AV[(size_t)(m0 + m) * Nn + n0 + r0 + x4 * 4];
            floatx4 o;
            o.x = Ls[(r0 + x4 * 4 + 0) * 68 + m] * a.x;
            o.y = Ls[(r0 + x4 * 4 + 1) * 68 + m] * a.y;
            o.z = Ls[(r0 + x4 * 4 + 2) * 68 + m] * a.z;
            o.w = Ls[(r0 + x4 * 4 + 3) * 68 + m] * a.w;
            *(floatx4*)&Lst[m * 68 + r0 + x4 * 4] = o;
        }
    }
    __syncthreads();

    const int tr = t >> 4, tc = t & 15;
    // GEMM1: parts[2j+qc][b, n0+4tr+ii, 4tc..] = sum_k Lsn[4tr+ii][k] * HW[m0+k][4tc..]
    {
        floatx4 acc[4];
        #pragma unroll
        for (int ii = 0; ii < 4; ++ii) acc[ii] = (floatx4){0.f, 0.f, 0.f, 0.f};
        #pragma unroll
        for (int k4 = 0; k4 < 64; k4 += 4) {
            floatx4 bmat[4];
            #pragma unroll
            for (int u = 0; u < 4; ++u)
                bmat[u] = *(const floatx4*)&HW[(size_t)(m0 + k4 + u) * 64 + tc * 4];
            #pragma unroll
            for (int ii = 0; ii < 4; ++ii) {
                floatx4 av = *(const floatx4*)&Lsn[(tr * 4 + ii) * 68 + k4];
                acc[ii] += av.x * bmat[0];
                acc[ii] += av.y * bmat[1];
                acc[ii] += av.z * bmat[2];
                acc[ii] += av.w * bmat[3];
            }
        }
        const size_t kbase = ((size_t)(j * 2 + qc) * (Bb * Nn) + (size_t)b * Nn + n0) * 64;
        #pragma unroll
        for (int ii = 0; ii < 4; ++ii)
            *(floatx4*)&parts[kbase + (size_t)(tr * 4 + ii) * 64 + tc * 4] = acc[ii];
    }
    // GEMM2 (off-diag): parts[2i+qr][b, m0+4tr+ii, ..] = sum_k Lst[4tr+ii][k] * HW[n0+k][..]
    if (i != j) {
        floatx4 acc[4];
        #pragma unroll
        for (int ii = 0; ii < 4; ++ii) acc[ii] = (floatx4){0.f, 0.f, 0.f, 0.f};
        #pragma unroll
        for (int k4 = 0; k4 < 64; k4 += 4) {
            floatx4 bmat[4];
            #pragma unroll
            for (int u = 0; u < 4; ++u)
                bmat[u] = *(const floatx4*)&HW[(size_t)(n0 + k4 + u) * 64 + tc * 4];
            #pragma unroll
            for (int ii = 0; ii < 4; ++ii) {
                floatx4 av = *(const floatx4*)&Lst[(tr * 4 + ii) * 68 + k4];
                acc[ii] += av.x * bmat[0];
                acc[ii] += av.y * bmat[1];
                acc[ii] += av.z * bmat[2];
                acc[ii] += av.w * bmat[3];
            }
        }
        const size_t kbase = ((size_t)(i * 2 + qr) * (Bb * Nn) + (size_t)b * Nn + m0) * 64;
        #pragma unroll
        for (int ii = 0; ii < 4; ++ii)
            *(floatx4*)&parts[kbase + (size_t)(tr * 4 + ii) * 64 + tc * 4] = acc[ii];
    }
}

// out[b,n,d] = bias[d] + sum_{k=0..15} parts[k][b,n,d]
__global__ __launch_bounds__(256) void reduce_kernel(const float* __restrict__ parts,
                                                     const float* __restrict__ bias,
                                                     float* __restrict__ out) {
    size_t e0 = ((size_t)blockIdx.x * 256 + threadIdx.x) * 4;
    floatx4 acc = *(const floatx4*)&bias[e0 & 63];
    #pragma unroll
    for (int k = 0; k < 16; ++k)
        acc += *(const floatx4*)&parts[(size_t)k * (Bb * Nn * 64) + e0];
    *(floatx4*)&out[e0] = acc;
}

extern "C" void kernel_launch(void* const* d_in, const int* in_sizes, int n_in,
                              void* d_out, int out_size, void* d_ws, size_t ws_size,
                              hipStream_t stream) {
    const float* H_v    = (const float*)d_in[0];
    const float* H_e    = (const float*)d_in[1];
    // d_in[2] = adj_e : UNUSED by the reference output
    const float* adj_v  = (const float*)d_in[3];
    const float* T      = (const float*)d_in[4];
    const float* weight = (const float*)d_in[5];
    const float* p      = (const float*)d_in[6];
    const float* bias   = (const float*)d_in[7];
    float* out = (float*)d_out;

    char* ws = (char*)d_ws;
    float* scale          = (float*)ws;                                      // 64 KB
    float* HWo            = (float*)(ws + (1 << 16));                        // 512 KB
    unsigned short* Tsc   = (unsigned short*)(ws + (1 << 20));               // 32 MB
    unsigned short* Tpl   = (unsigned short*)(ws + (1 << 20) + (32u << 20)); // 32 MB
    unsigned short* Ppart = (unsigned short*)(ws + (1 << 20) + (64u << 20)); // 16.5 MB bf16
    float* parts          = (float*)(ws + (1 << 20) + (82u << 20));          // 8 MB fp32, 16 slices

    // Output chunk 1: H_e passthrough (fp32, exact)
    hipMemcpyAsync(out + (size_t)Bb * Nn * DV, H_e,
                   (size_t)Bb * Ee * 64 * sizeof(float),
                   hipMemcpyDeviceToDevice, stream);

    scale_kernel<<<dim3(Bb * Ee / 4), dim3(256), 0, stream>>>(H_e, p, scale);
    cast_kernel<<<dim3((Bb * Nn * Ee / 4) / 256), dim3(256), 0, stream>>>(T, scale, Tsc, Tpl);
    hw_kernel<<<dim3(Bb * Nn / 4), dim3(256), 0, stream>>>(H_v, weight, HWo);
    mm_kernel<<<dim3(36, Bb, 7), dim3(256), 0, stream>>>(Tsc, Tpl, Ppart);
    fuse_kernel<<<dim3(36 * Bb, 4), dim3(256), 0, stream>>>(Ppart, adj_v, HWo, parts);
    reduce_kernel<<<dim3((Bb * Nn * 64 / 4) / 256), dim3(256), 0, stream>>>(parts, bias, out);
}